// Round 16
// baseline (1216.772 us; speedup 1.0000x reference)
//
#include <hip/hip_runtime.h>

#define TT 512
#define BB 64
#define II 512
#define LL 1024
#define GROUPS 16
#define RPG 4            // batch rows per group
#define WPG 8            // WGs per group (128 cols each)
#define NWGS (GROUPS * WPG)

typedef __bf16 bf16x8 __attribute__((ext_vector_type(8)));
typedef float f32x4 __attribute__((ext_vector_type(4)));
typedef unsigned int u32x4 __attribute__((ext_vector_type(4)));

// ---------- workspace layout (bytes) ----------
// wsWi : Wi frag-ordered bf16 (xi_gemm)                          = 1 MiB
// wsWh2: Wh frag-ordered bf16 [8 w][8 wv][32 ks][64 l][8e]       = 2 MiB
// hbuf : ping-pong compact H  2 x [16 g][32 ks][4 kq][4 r][8e]   = 256 KiB
//        readiness tag = LSB of even elements of each 16B chunk
#define WSWI_OFF 0u
#define WSWH_OFF (1u << 20)
#define HBUF_OFF (3u << 20)

__device__ __forceinline__ unsigned short f2bf(float f) {
  unsigned int u = __builtin_bit_cast(unsigned int, f);
  u += 0x7fffu + ((u >> 16) & 1u);   // round-to-nearest-even (inputs finite)
  return (unsigned short)(u >> 16);
}

__device__ __forceinline__ bf16x8 ld_frag(const unsigned short* p) {
  return __builtin_bit_cast(bf16x8, *(const uint4*)p);
}

// ============================================================
// prep: frag-order Wi (xi_gemm), Wh2 (scan), compact h0 (tag=0),
//       seed hbuf ping buffer 1 with tag=1 (t=1 false-positive guard).
// ============================================================
__global__ __launch_bounds__(256) void prep_kernel(
    const float* __restrict__ h0, const float* __restrict__ Wi,
    const float* __restrict__ Wh, unsigned short* __restrict__ wsWi,
    unsigned short* __restrict__ wsWh2, unsigned short* __restrict__ hbuf) {
  int idx = blockIdx.x * 256 + threadIdx.x;
  const float* src;
  unsigned short* dst;
  bool tagme = false;
  if (idx < 65536) {                       // Wi slots (for xi_gemm)
    int ln = idx & 63, s = idx >> 6;
    int nsub = s & 7, s2 = s >> 3, ks = s2 & 15, bn = s2 >> 4;
    int n = bn * 128 + nsub * 16 + (ln & 15);
    int k = ks * 32 + (ln >> 4) * 8;
    src = Wi + (size_t)n * II + k;
    dst = wsWi + (size_t)idx * 8;
  } else if (idx < 196608) {               // Wh2 slots [w:8][wv:8][ks:32][l:64]
    int o = idx - 65536;
    int l = o & 63, s = o >> 6;
    int ks = s & 31, s2 = s >> 5;
    int wvp = s2 & 7, wp = s2 >> 3;
    int col = wp * 128 + wvp * 16 + (l & 15);
    int k = ks * 32 + (l >> 4) * 8;
    src = Wh + (size_t)col * LL + k;
    dst = wsWh2 + (size_t)o * 8;
  } else if (idx < 204800) {               // h0 compact slots [g][ks][kq][r][8e]
    int o = idx - 196608;
    int r = o & 3, kq = (o >> 2) & 3, ks = (o >> 4) & 31, g = o >> 9;
    src = h0 + (size_t)(g * RPG + r) * LL + ks * 32 + kq * 8;
    dst = hbuf + (size_t)o * 8;
    tagme = true;
  } else if (idx < 212992) {               // seed ping buffer 1: tag = 1
    int o = idx - 204800;
    uint4 p = {0x00010001u, 0x00010001u, 0x00010001u, 0x00010001u};
    *(uint4*)(hbuf + 65536 + (size_t)o * 8) = p;
    return;
  } else {
    return;
  }
  float4 a0 = *(const float4*)src;
  float4 a1 = *(const float4*)(src + 4);
  uint4 p;
  p.x = f2bf(a0.x) | ((unsigned)f2bf(a0.y) << 16);
  p.y = f2bf(a0.z) | ((unsigned)f2bf(a0.w) << 16);
  p.z = f2bf(a1.x) | ((unsigned)f2bf(a1.y) << 16);
  p.w = f2bf(a1.z) | ((unsigned)f2bf(a1.w) << 16);
  if (tagme) {                             // h0 tag = 0 on all even elements
    p.x &= ~1u; p.y &= ~1u; p.z &= ~1u; p.w &= ~1u;
  }
  *(uint4*)dst = p;
}

// ============================================================
// xi = x @ Wi^T + bi  -> d_out (reused as xi buffer) [unchanged]
// ============================================================
__global__ __launch_bounds__(256) void xi_gemm(
    const float* __restrict__ x, const float* __restrict__ bi,
    const unsigned short* __restrict__ wsWi, float* __restrict__ out) {
  __shared__ unsigned short As[8 * 64 * 8];
  __shared__ unsigned short Bs[8 * 64 * 8];
  const int tid = threadIdx.x;
  const int ln = tid & 63;
  const int wv = tid >> 6;
  const int wm = wv >> 1, wn = wv & 1;
  const int bn = blockIdx.x;
  const int Mbase = blockIdx.y * 128;
  const int Nbase = bn * 128;

  f32x4 acc[4][4] = {};

  for (int ks = 0; ks < 16; ++ks) {
    __syncthreads();
#pragma unroll
    for (int i = 0; i < 2; ++i) {
      int slot = tid + 256 * i;
      int msub = slot >> 6;
      int l2 = slot & 63;
      const float* src =
          x + (size_t)(Mbase + msub * 16 + (l2 & 15)) * II + ks * 32 + (l2 >> 4) * 8;
      float4 a0 = *(const float4*)src;
      float4 a1 = *(const float4*)(src + 4);
      uint4 p;
      p.x = f2bf(a0.x) | ((unsigned)f2bf(a0.y) << 16);
      p.y = f2bf(a0.z) | ((unsigned)f2bf(a0.w) << 16);
      p.z = f2bf(a1.x) | ((unsigned)f2bf(a1.y) << 16);
      p.w = f2bf(a1.z) | ((unsigned)f2bf(a1.w) << 16);
      *(uint4*)(As + slot * 8) = p;
      const uint4* bsrc = (const uint4*)(wsWi + (size_t)(bn * 16 + ks) * 4096) + slot;
      *(uint4*)(Bs + slot * 8) = *bsrc;
    }
    __syncthreads();
    bf16x8 af[4];
#pragma unroll
    for (int m = 0; m < 4; ++m)
      af[m] = ld_frag(As + ((wm * 4 + m) * 64 + ln) * 8);
#pragma unroll
    for (int n = 0; n < 4; ++n) {
      bf16x8 bf = ld_frag(Bs + ((wn * 4 + n) * 64 + ln) * 8);
#pragma unroll
      for (int m = 0; m < 4; ++m)
        acc[m][n] = __builtin_amdgcn_mfma_f32_16x16x32_bf16(af[m], bf, acc[m][n], 0, 0, 0);
    }
  }
#pragma unroll
  for (int n = 0; n < 4; ++n) {
    int col = Nbase + wn * 64 + n * 16 + (ln & 15);
    float bv = bi[col];
#pragma unroll
    for (int m = 0; m < 4; ++m) {
      int row0 = Mbase + wm * 64 + m * 16 + (ln >> 4) * 4;
#pragma unroll
      for (int r = 0; r < 4; ++r)
        out[(size_t)(row0 + r) * LL + col] = acc[m][n][r] + bv;
    }
  }
}

// ============================================================
// Batch-grouped persistent scan v9 — flagless data-tagged,
// B pinned in AGPRs, 512-thread WGs (8/group, 1 chunk/thread
// poll), deferred out-store (drains under next step's MFMA).
// ============================================================
__global__ __launch_bounds__(512, 1) void scan_kernel(
    const unsigned short* __restrict__ wsWh2, float* __restrict__ out,
    unsigned short* __restrict__ hbuf) {
  __shared__ unsigned short hA[2][4096];      // 2 x 8 KiB compact H
  __shared__ unsigned short packb[8][64];     // per-wave pack, 128 B each

  const int tid = threadIdx.x;
  const int ln = tid & 63;
  const int wv = tid >> 6;                 // 0..7 : 16-col subtile
  const int g = blockIdx.x >> 3;           // group (0..15)
  const int w = blockIdx.x & 7;            // 128-col slice within group
  const int kq = ln >> 4;                  // batch row this lane owns
  const int rdup = ln & 3;
  const int cc = ln & 15;                  // col within wave's 16
  const int ks_w = w * 4 + (wv >> 1);      // wave's compact-h ks slot
  const int half = wv & 1;

  // ---- B-frags pinned via asm loads (32 x 16B; lands in AGPRs) ----
  u32x4 Breg[32];
  {
    const unsigned short* bsrc = wsWh2 + (size_t)(w * 8 + wv) * 16384 + ln * 8;
#pragma unroll
    for (int i = 0; i < 8; ++i) {
      const unsigned short* bp = bsrc + i * 2048;   // 4 ks per iter (4 KB)
      asm volatile(
          "global_load_dwordx4 %0, %4, off\n\t"
          "global_load_dwordx4 %1, %4, off offset:1024\n\t"
          "global_load_dwordx4 %2, %4, off offset:2048\n\t"
          "global_load_dwordx4 %3, %4, off offset:3072"
          : "=&v"(Breg[i * 4]), "=&v"(Breg[i * 4 + 1]),
            "=&v"(Breg[i * 4 + 2]), "=&v"(Breg[i * 4 + 3])
          : "v"(bp) : "memory");
    }
    asm volatile("s_waitcnt vmcnt(0)" ::: "memory");
    __builtin_amdgcn_sched_barrier(0);
  }

  const int c0 = tid;                      // this thread's single 16B chunk

  // my output cell (row kq of group, col w*128+wv*16+cc); also my xi address
  const size_t ocell = (size_t)(g * RPG + kq) * LL + w * 128 + wv * 16 + cc;

  // ---- prologue: prefetch xi(0) ----
  float xv_next;
  asm volatile("global_load_dword %0, %1, off"
               : "=&v"(xv_next) : "v"(out + ocell) : "memory");
  float prev_hval = 0.0f;

  for (int t = 0; t < TT; ++t) {
    const unsigned ptag = (unsigned)((t >> 1) & 1);        // expected tag
    const unsigned ntag = (unsigned)(((t + 1) >> 1) & 1);  // tag for h_{t+1}

    // ---- poll-gather: re-load own chunk until all 4 tags match ----
    const unsigned short* hcur = hbuf + (size_t)(t & 1) * 65536 + g * 4096;
    const unsigned short* p0 = hcur + c0 * 8;
    u32x4 hv0;
    {
      int good;
      do {
        asm volatile(
            "global_load_dwordx4 %0, %1, off sc1\n\t"
            "s_waitcnt vmcnt(0)"
            : "=&v"(hv0) : "v"(p0) : "memory");
        good = ((hv0[0] & 1) == ptag) & ((hv0[1] & 1) == ptag) &
               ((hv0[2] & 1) == ptag) & ((hv0[3] & 1) == ptag);
      } while (__all(good) == 0);
    }
    __builtin_amdgcn_sched_barrier(0);
    unsigned short* hw = hA[t & 1];
    *(u32x4*)(hw + c0 * 8) = hv0;
    float xv = xv_next;                    // xi landed under the poll
    __syncthreads();                       // the ONE block barrier per step

    // ---- deferred out-store for t-1 (drains under MFMA, off poll path) ----
    if (t > 0)
      asm volatile("global_store_dword %0, %1, off"
                   :: "v"(out + (size_t)(t - 1) * 65536 + ocell), "v"(prev_hval)
                   : "memory");

    // ---- MFMA: K=1024, A from LDS (broadcast reads), B pinned ----
    f32x4 a0 = {}, a1 = {}, a2 = {}, a3 = {};
#pragma unroll
    for (int ks = 0; ks < 32; ks += 4) {
      bf16x8 A0 = ld_frag(hw + (ks * 16 + kq * 4 + rdup) * 8);
      bf16x8 A1 = ld_frag(hw + ((ks + 1) * 16 + kq * 4 + rdup) * 8);
      bf16x8 A2 = ld_frag(hw + ((ks + 2) * 16 + kq * 4 + rdup) * 8);
      bf16x8 A3 = ld_frag(hw + ((ks + 3) * 16 + kq * 4 + rdup) * 8);
      a0 = __builtin_amdgcn_mfma_f32_16x16x32_bf16(
          A0, __builtin_bit_cast(bf16x8, Breg[ks]), a0, 0, 0, 0);
      a1 = __builtin_amdgcn_mfma_f32_16x16x32_bf16(
          A1, __builtin_bit_cast(bf16x8, Breg[ks + 1]), a1, 0, 0, 0);
      a2 = __builtin_amdgcn_mfma_f32_16x16x32_bf16(
          A2, __builtin_bit_cast(bf16x8, Breg[ks + 2]), a2, 0, 0, 0);
      a3 = __builtin_amdgcn_mfma_f32_16x16x32_bf16(
          A3, __builtin_bit_cast(bf16x8, Breg[ks + 3]), a3, 0, 0, 0);
    }
    f32x4 s = (a0 + a1) + (a2 + a3);

    // ---- all-lane epilogue: lane owns (row kq, col cc) ----
    float hval = tanhf(s[kq] + xv);
    unsigned short hbf = f2bf(hval);
    if ((cc & 1) == 0)                     // even elements carry the tag
      hbf = (unsigned short)((hbf & ~1u) | ntag);
    packb[wv][(cc >> 3) * 32 + kq * 8 + (cc & 7)] = hbf;
    asm volatile("s_waitcnt lgkmcnt(0)" ::: "memory");
    __builtin_amdgcn_sched_barrier(0);

    // ---- publish h (sc1) — no drain, no flag ----
    unsigned short* hnext = hbuf + (size_t)((t + 1) & 1) * 65536 + g * 4096;
    if (ln < 8) {
      u32x4 pk = *(const u32x4*)(&packb[wv][ln * 8]);
      unsigned short* dp = hnext + ks_w * 128 + half * 64 + ln * 8;
      asm volatile("global_store_dwordx4 %0, %1, off sc1"
                   :: "v"(dp), "v"(pk) : "memory");
    }
    prev_hval = hval;
    // ---- xi prefetch for t+1 (mostly drains before next poll) ----
    {
      int tn = (t + 1 < TT) ? (t + 1) : t;
      asm volatile("global_load_dword %0, %1, off"
                   : "=&v"(xv_next) : "v"(out + (size_t)tn * 65536 + ocell)
                   : "memory");
    }
  }
  // tail: final deferred out-store
  asm volatile("global_store_dword %0, %1, off"
               :: "v"(out + (size_t)(TT - 1) * 65536 + ocell), "v"(prev_hval)
               : "memory");
}

extern "C" void kernel_launch(void* const* d_in, const int* in_sizes, int n_in,
                              void* d_out, int out_size, void* d_ws, size_t ws_size,
                              hipStream_t stream) {
  const float* x  = (const float*)d_in[0];
  const float* h0 = (const float*)d_in[1];
  const float* Wi = (const float*)d_in[2];
  const float* bi = (const float*)d_in[3];
  const float* Wh = (const float*)d_in[4];
  float* out = (float*)d_out;
  char* ws = (char*)d_ws;
  unsigned short* wsWi  = (unsigned short*)(ws + WSWI_OFF);
  unsigned short* wsWh2 = (unsigned short*)(ws + WSWH_OFF);
  unsigned short* hbuf  = (unsigned short*)(ws + HBUF_OFF);

  prep_kernel<<<832, 256, 0, stream>>>(h0, Wi, Wh, wsWi, wsWh2, hbuf);
  xi_gemm<<<dim3(8, 256), 256, 0, stream>>>(x, bi, wsWi, out);
  void* args[] = {(void*)&wsWh2, (void*)&out, (void*)&hbuf};
  (void)hipLaunchCooperativeKernel(reinterpret_cast<void*>(scan_kernel),
                                   dim3(NWGS), dim3(512), args, 0, stream);
}